// Round 9
// baseline (129.453 us; speedup 1.0000x reference)
//
#include <hip/hip_runtime.h>

#define T_DIM 2048
#define B_DIM 8192
#define GAMMA 0.99f
#define NCHUNK 256
#define CHUNK_L 8            // rows per chunk (NCHUNK*CHUNK_L == T_DIM)

typedef float v4f __attribute__((ext_vector_type(4)));

__device__ __forceinline__ void nt_store4f(float* p, float4 x) {
    __builtin_nontemporal_store(*(v4f*)&x, (v4f*)p);
}

// ---------------------------------------------------------------------------
// Pass 1 (HBM -> LDS DMA): per-wave-private LDS tiles, global_load_lds
// width=16 (bypasses the VGPR load-return path entirely, no register
// pressure -> no spill trap). Two phases per block: rows 4..7 then rows 0..3
// (composite chains r high->low). Counted vmcnt waits; rho leaves via NT.
// No __syncthreads anywhere: each wave stages and consumes only its own tile.
// ---------------------------------------------------------------------------
__global__ __launch_bounds__(256) void vtrace_pass1(
    const float* __restrict__ v, const float* __restrict__ rew,
    const float* __restrict__ tlp, const float* __restrict__ blp,
    float* __restrict__ out_rho,    // d_out + T*B (final)
    float* __restrict__ Aw, float* __restrict__ Bw)
{
    // [wave][stream][row][col] : 4*4*4*256*4B = 64 KB -> 2 blocks/CU
    __shared__ float lds[4][4][4][256];

    const int w    = threadIdx.x >> 6;          // wave id 0..3
    const int lane = threadIdx.x & 63;
    const int c    = blockIdx.y;
    const int col0 = blockIdx.x * 1024 + w * 256;   // wave's 256-col range
    const int col  = col0 + lane * 4;
    const bool last_chunk = (c == NCHUNK - 1);

    const float* const src0 = tlp;   // stream order: tlp, blp, v, rew
    const float* const src1 = blp;
    const float* const src2 = v;
    const float* const src3 = rew;

    float4 A  = make_float4(0.f, 0.f, 0.f, 0.f);
    float4 Bc = make_float4(1.f, 1.f, 1.f, 1.f);

    // two phases: ph=0 -> rows 4..7, ph=1 -> rows 0..3
    #pragma unroll
    for (int ph = 0; ph < 2; ++ph) {
        const int r0 = ph ? 0 : 4;

        // ---- issue 16 DMA (4 rows x 4 streams), oldest = tlp,blp ----
        #pragma unroll
        for (int r = 0; r < 4; ++r)
            __builtin_amdgcn_global_load_lds(
                (const unsigned int*)(src0 + (size_t)(c * CHUNK_L + r0 + r) * B_DIM + col0) + lane * 4,
                (unsigned int*)&lds[w][0][r][0], 16, 0, 0);
        #pragma unroll
        for (int r = 0; r < 4; ++r)
            __builtin_amdgcn_global_load_lds(
                (const unsigned int*)(src1 + (size_t)(c * CHUNK_L + r0 + r) * B_DIM + col0) + lane * 4,
                (unsigned int*)&lds[w][1][r][0], 16, 0, 0);
        #pragma unroll
        for (int r = 0; r < 4; ++r)
            __builtin_amdgcn_global_load_lds(
                (const unsigned int*)(src2 + (size_t)(c * CHUNK_L + r0 + r) * B_DIM + col0) + lane * 4,
                (unsigned int*)&lds[w][2][r][0], 16, 0, 0);
        #pragma unroll
        for (int r = 0; r < 4; ++r)
            __builtin_amdgcn_global_load_lds(
                (const unsigned int*)(src3 + (size_t)(c * CHUNK_L + r0 + r) * B_DIM + col0) + lane * 4,
                (unsigned int*)&lds[w][3][r][0], 16, 0, 0);

        // ---- wait for tlp,blp (8 oldest); v,rew (+old NT stores) in flight ----
        asm volatile("s_waitcnt vmcnt(8)" ::: "memory");
        __builtin_amdgcn_sched_barrier(0);

        float4 rho[4];
        #pragma unroll
        for (int r = 0; r < 4; ++r) {
            const float4 t4 = *(const float4*)&lds[w][0][r][lane * 4];
            const float4 b4 = *(const float4*)&lds[w][1][r][lane * 4];
            rho[r].x = fminf(1.f, __expf(t4.x - b4.x));
            rho[r].y = fminf(1.f, __expf(t4.y - b4.y));
            rho[r].z = fminf(1.f, __expf(t4.z - b4.z));
            rho[r].w = fminf(1.f, __expf(t4.w - b4.w));
            nt_store4f(out_rho + (size_t)(c * CHUNK_L + r0 + r) * B_DIM + col, rho[r]);
        }

        // ---- wait for v,rew (only the 4 fresh NT stores may remain) ----
        asm volatile("s_waitcnt vmcnt(4)" ::: "memory");
        __builtin_amdgcn_sched_barrier(0);

        // ---- composite over this phase's rows, r = 3..0 (global high->low) ----
        #pragma unroll
        for (int r = 3; r >= 0; --r) {
            const float4 v4 = *(const float4*)&lds[w][2][r][lane * 4];
            const float4 r4 = *(const float4*)&lds[w][3][r][lane * 4];
            float4 a4, bv;
            if (last_chunk && r0 + r == CHUNK_L - 1) {   // global row T-1
                a4 = v4;
                bv = make_float4(0.f, 0.f, 0.f, 0.f);
            } else {
                a4.x = fmaf(rho[r].x, r4.x - v4.x, v4.x);
                a4.y = fmaf(rho[r].y, r4.y - v4.y, v4.y);
                a4.z = fmaf(rho[r].z, r4.z - v4.z, v4.z);
                a4.w = fmaf(rho[r].w, r4.w - v4.w, v4.w);
                bv.x = GAMMA * rho[r].x;
                bv.y = GAMMA * rho[r].y;
                bv.z = GAMMA * rho[r].z;
                bv.w = GAMMA * rho[r].w;
            }
            A.x = fmaf(bv.x, A.x, a4.x);
            A.y = fmaf(bv.y, A.y, a4.y);
            A.z = fmaf(bv.z, A.z, a4.z);
            A.w = fmaf(bv.w, A.w, a4.w);
            Bc.x *= bv.x; Bc.y *= bv.y; Bc.z *= bv.z; Bc.w *= bv.w;
        }

        // before phase 2's DMA overwrites this LDS: all ds_reads must be done
        if (ph == 0) {
            asm volatile("s_waitcnt lgkmcnt(0)" ::: "memory");
            __builtin_amdgcn_sched_barrier(0);
        }
    }

    const int widx = c * B_DIM + col;
    *(float4*)(Aw + widx) = A;        // small, cached (read by carry)
    *(float4*)(Bw + widx) = Bc;
}

// ---------------------------------------------------------------------------
// Pass 2: per-column right-to-left scan of chunk composites -> carries.
// cb[c] = value entering chunk c from the right, i.e. out[(c+1)*L].
// ---------------------------------------------------------------------------
__global__ __launch_bounds__(256) void vtrace_carry(
    const float* __restrict__ Aw, const float* __restrict__ Bw,
    float* __restrict__ cb)
{
    const int j = blockIdx.x * blockDim.x + threadIdx.x;  // 0 .. B-1
    float x = 0.f;
    #pragma unroll 8
    for (int c = NCHUNK - 1; c >= 0; --c) {
        const int i = c * B_DIM + j;
        const float Av = Aw[i];
        const float Bv = Bw[i];
        cb[i] = x;
        x = fmaf(Bv, x, Av);
    }
}

// ---------------------------------------------------------------------------
// Pass 3: RECOMPUTE rho/a from the (cache-warm) inputs, sweep the chunk
// bottom-up, NT-store vtrace. (Measured ~12-17 TB/s warm; unchanged.)
// ---------------------------------------------------------------------------
__global__ __launch_bounds__(256) void vtrace_apply(
    const float* __restrict__ v, const float* __restrict__ rew,
    const float* __restrict__ tlp, const float* __restrict__ blp,
    float* __restrict__ out_v,           // d_out vtrace slot (final)
    const float* __restrict__ cb)
{
    const int j    = blockIdx.x * blockDim.x + threadIdx.x;  // 0 .. B/4-1
    const int c    = blockIdx.y;
    const int col  = j * 4;
    const int base = c * CHUNK_L * B_DIM + col;
    const bool last_chunk = (c == NCHUNK - 1);

    float4 t4[CHUNK_L], b4[CHUNK_L];
    #pragma unroll
    for (int r = 0; r < CHUNK_L; ++r)
        t4[r] = *(const float4*)(tlp + base + r * B_DIM);
    #pragma unroll
    for (int r = 0; r < CHUNK_L; ++r)
        b4[r] = *(const float4*)(blp + base + r * B_DIM);
    __builtin_amdgcn_sched_barrier(0);

    float4 rho[CHUNK_L];
    #pragma unroll
    for (int r = 0; r < CHUNK_L; ++r) {
        rho[r].x = fminf(1.f, __expf(t4[r].x - b4[r].x));
        rho[r].y = fminf(1.f, __expf(t4[r].y - b4[r].y));
        rho[r].z = fminf(1.f, __expf(t4[r].z - b4[r].z));
        rho[r].w = fminf(1.f, __expf(t4[r].w - b4[r].w));
    }

    float4 v4[CHUNK_L], r4[CHUNK_L];
    #pragma unroll
    for (int r = 0; r < CHUNK_L; ++r)
        v4[r] = *(const float4*)(v + base + r * B_DIM);
    #pragma unroll
    for (int r = 0; r < CHUNK_L; ++r)
        r4[r] = *(const float4*)(rew + base + r * B_DIM);
    __builtin_amdgcn_sched_barrier(0);

    float4 x = *(const float4*)(cb + c * B_DIM + col);  // out[(c+1)*L]

    #pragma unroll
    for (int r = CHUNK_L - 1; r >= 0; --r) {
        float4 a4, bv;
        if (last_chunk && r == CHUNK_L - 1) {        // global row T-1
            a4 = v4[r];
            bv = make_float4(0.f, 0.f, 0.f, 0.f);
        } else {
            a4.x = fmaf(rho[r].x, r4[r].x - v4[r].x, v4[r].x);
            a4.y = fmaf(rho[r].y, r4[r].y - v4[r].y, v4[r].y);
            a4.z = fmaf(rho[r].z, r4[r].z - v4[r].z, v4[r].z);
            a4.w = fmaf(rho[r].w, r4[r].w - v4[r].w, v4[r].w);
            bv.x = GAMMA * rho[r].x;
            bv.y = GAMMA * rho[r].y;
            bv.z = GAMMA * rho[r].z;
            bv.w = GAMMA * rho[r].w;
        }
        x.x = fmaf(bv.x, x.x, a4.x);
        x.y = fmaf(bv.y, x.y, a4.y);
        x.z = fmaf(bv.z, x.z, a4.z);
        x.w = fmaf(bv.w, x.w, a4.w);
        nt_store4f(out_v + base + r * B_DIM, x);
    }
}

extern "C" void kernel_launch(void* const* d_in, const int* in_sizes, int n_in,
                              void* d_out, int out_size, void* d_ws, size_t ws_size,
                              hipStream_t stream) {
    const float* v   = (const float*)d_in[0];
    const float* rew = (const float*)d_in[1];
    const float* tlp = (const float*)d_in[2];
    const float* blp = (const float*)d_in[3];

    float* out_v   = (float*)d_out;                          // vtrace slot
    float* out_rho = out_v + (size_t)T_DIM * B_DIM;          // rhos slot

    float* Aw = (float*)d_ws;                                // NCHUNK*B floats
    float* Bw = Aw + (size_t)NCHUNK * B_DIM;                 // NCHUNK*B floats
    float* cb = Bw + (size_t)NCHUNK * B_DIM;                 // NCHUNK*B floats

    dim3 blk(256);
    dim3 grid_p1(B_DIM / 1024, NCHUNK);                      // (8, 256)
    dim3 grid_ap(B_DIM / 4 / 256, NCHUNK);                   // (8, 256)

    vtrace_pass1<<<grid_p1, blk, 0, stream>>>(v, rew, tlp, blp,
                                              out_rho, Aw, Bw);
    vtrace_carry<<<dim3(B_DIM / 256), blk, 0, stream>>>(Aw, Bw, cb);
    vtrace_apply<<<grid_ap, blk, 0, stream>>>(v, rew, tlp, blp,
                                              out_v, cb);
}